// Round 14
// baseline (528.597 us; speedup 1.0000x reference)
//
#include <hip/hip_runtime.h>
#include <hip/hip_bf16.h>

// Model_39676907885326: out = softmax(causal(q)) @ e
//   e[i,j,l]  = sum_k in[i,j,k] * w[l,k,j]
//   attn[i,j,l] = softmax_{l<=j}( (sum_k in[i,j,k]) * w[i,j,l] / (0.5 + sum_l w[i,j,l]) )
//   out[i]    = attn[i] @ e[i]
//
// Pipeline (ws regions):
//   R0 [0, N3) bf16        : wt[j][l][k]  ->  et[i][l][m]
//   R1 [N3, 2*N3) bf16     : e[i][j][l]   ->  attn[i][j][m]
//   RS [2*N3 ..) fp32 N2   : rs[i][j]
//   kT -> k_e5(+rs) -> k_eT -> k_attn(rs) -> k_av3
//
// R14: k_e tile 64x128 -> 128x192. Theory: k_e is L2->CU-traffic-bound
// (343KB/block, 1.36GB total ~ the 130us plateau). 128x192 cuts L2-side
// traffic 42% (790MB) and triples MFMA-per-barrier (16->48/wave). 40KB LDS,
// (256,3), 3 blocks/CU, grid 2304 = exactly 3 rounds. k_av3 et al = r11.

#define N 384
#define N2 (N * N)
#define BK 64
static const size_t N3 = (size_t)N * N * N;

typedef __attribute__((ext_vector_type(8))) short s16x8;
typedef __attribute__((ext_vector_type(4))) float f32x4;

#define AS1 __attribute__((address_space(1)))
#define AS3 __attribute__((address_space(3)))
__device__ __forceinline__ void gll16(const void* g, void* l) {
    __builtin_amdgcn_global_load_lds((const AS1 unsigned int*)g,
                                     (AS3 unsigned int*)l, 16, 0, 0);
}
#define WAITL0 asm volatile("s_waitcnt lgkmcnt(0)" ::: "memory")
#define BAR    __builtin_amdgcn_s_barrier()

__device__ __forceinline__ unsigned short f32_to_bf16(float f) {
    unsigned int u = __float_as_uint(f);
    u += 0x7FFFu + ((u >> 16) & 1u);
    return (unsigned short)(u >> 16);
}
__device__ __forceinline__ unsigned int pk2(float a, float b) {
    return (unsigned int)f32_to_bf16(a) | ((unsigned int)f32_to_bf16(b) << 16);
}

// ---------------------------------------------------------------------------
// kT: wt[j*N2 + r] = bf16(w[r*N + j]), r = l*N+k
// ---------------------------------------------------------------------------
__global__ __launch_bounds__(256) void kT(const float* __restrict__ w,
                                          unsigned short* __restrict__ wt) {
    __shared__ unsigned short tile[64][68];
    const int r0 = blockIdx.x * 64;
    const int j0 = blockIdx.y * 64;
    const int tx = threadIdx.x & 63;
    const int ty = threadIdx.x >> 6;
#pragma unroll
    for (int p = 0; p < 16; ++p) {
        const int r = ty * 16 + p;
        tile[r][tx] = f32_to_bf16(w[(size_t)(r0 + r) * N + j0 + tx]);
    }
    __syncthreads();
#pragma unroll
    for (int p = 0; p < 16; ++p) {
        const int jj = ty * 16 + p;
        wt[(size_t)(j0 + jj) * N2 + r0 + tx] = tile[tx][jj];
    }
}

// ---------------------------------------------------------------------------
// k_e5: per j: e[i0..i0+127, j, l0..l0+191] = in[i,j,:] . wt[j][l][:]
// BM=128, BN=192, BK=64, 4 waves (2x2, wave tile 64x96), acc[4][6].
// A reg-staged in two half-rounds (+fused rsum); B via gll. 40KB LDS.
// ---------------------------------------------------------------------------
__global__ __launch_bounds__(256, 3) void k_e5(const float* __restrict__ in,
                                               const unsigned short* __restrict__ wt,
                                               unsigned short* __restrict__ e,
                                               float* __restrict__ rs) {
    __shared__ union {
        struct { unsigned short A[128 * 64]; unsigned short B[192 * 64]; } s; // 40960 B
        unsigned short C[64 * 200];   // 25600 B
    } sm;

    const int lin = blockIdx.x;               // 2304 = 8 * 288
    const int swz = (lin & 7) * 288 + (lin >> 3);
    const int j   = swz / 6;
    const int sub = swz % 6;
    const int i0  = (sub >> 1) * 128;         // 0 / 128 / 256
    const int l0  = (sub & 1) * 192;          // 0 / 192

    const int t = threadIdx.x, lane = t & 63, wv = t >> 6;
    const int fr = lane & 15, fx = lane >> 4;
    const int wr = (wv >> 1) * 64;            // wave row offset (0/64)
    const int wc = (wv & 1) * 96;             // wave col offset (0/96)
    const int rb_off = lane >> 3;
    const int p8     = lane & 7;

    // A staging: thread -> row ra (0..127), chunk base cb (0 or 4); 4 chunks.
    const int ra = t >> 1, cb = (t & 1) * 4;
    const float* Ab = in + (size_t)(i0 + ra) * N2 + (size_t)j * N + cb * 8;
    unsigned short* AsRow = sm.s.A + ra * 64;

    const unsigned short* Wj = wt + (size_t)j * N2 + (size_t)l0 * N;

    f32x4 acc[4][6];
#pragma unroll
    for (int m = 0; m < 4; ++m)
#pragma unroll
        for (int n = 0; n < 6; ++n) acc[m][n] = (f32x4){0.f, 0.f, 0.f, 0.f};

    float rsum = 0.f;

    float4 va[4];   // chunks cb, cb+1 of current tile
    va[0] = *(const float4*)(Ab);
    va[1] = *(const float4*)(Ab + 4);
    va[2] = *(const float4*)(Ab + 8);
    va[3] = *(const float4*)(Ab + 12);

#pragma unroll
    for (int tt = 0; tt < 6; ++tt) {
        const int k0 = tt * 64;
        __syncthreads();
        // write chunks cb, cb+1 from prefetched va
        {
            rsum += (va[0].x + va[0].y + va[0].z + va[0].w) +
                    (va[1].x + va[1].y + va[1].z + va[1].w) +
                    (va[2].x + va[2].y + va[2].z + va[2].w) +
                    (va[3].x + va[3].y + va[3].z + va[3].w);
            uint4 a0, a1;
            a0.x = pk2(va[0].x, va[0].y); a0.y = pk2(va[0].z, va[0].w);
            a0.z = pk2(va[1].x, va[1].y); a0.w = pk2(va[1].z, va[1].w);
            a1.x = pk2(va[2].x, va[2].y); a1.y = pk2(va[2].z, va[2].w);
            a1.z = pk2(va[3].x, va[3].y); a1.w = pk2(va[3].z, va[3].w);
            *(uint4*)(AsRow + (((cb + 0) ^ (ra & 7)) * 8)) = a0;
            *(uint4*)(AsRow + (((cb + 1) ^ (ra & 7)) * 8)) = a1;
        }
        // second half: chunks cb+2, cb+3 (load now, in-step)
        {
            float4 w0 = *(const float4*)(Ab + k0 + 16);
            float4 w1 = *(const float4*)(Ab + k0 + 20);
            float4 w2 = *(const float4*)(Ab + k0 + 24);
            float4 w3 = *(const float4*)(Ab + k0 + 28);
            rsum += (w0.x + w0.y + w0.z + w0.w) +
                    (w1.x + w1.y + w1.z + w1.w) +
                    (w2.x + w2.y + w2.z + w2.w) +
                    (w3.x + w3.y + w3.z + w3.w);
            uint4 a2, a3;
            a2.x = pk2(w0.x, w0.y); a2.y = pk2(w0.z, w0.w);
            a2.z = pk2(w1.x, w1.y); a2.w = pk2(w1.z, w1.w);
            a3.x = pk2(w2.x, w2.y); a3.y = pk2(w2.z, w2.w);
            a3.z = pk2(w3.x, w3.y); a3.w = pk2(w3.z, w3.w);
            *(uint4*)(AsRow + (((cb + 2) ^ (ra & 7)) * 8)) = a2;
            *(uint4*)(AsRow + (((cb + 3) ^ (ra & 7)) * 8)) = a3;
        }
        // B via gll: 192 rows, wave covers 48
#pragma unroll
        for (int itb = 0; itb < 6; ++itb) {
            const int rb = wv * 48 + itb * 8 + rb_off;
            const int sc = p8 ^ (rb & 7);
            gll16(Wj + (size_t)rb * N + k0 + sc * 8,
                  sm.s.B + (wv * 48 + itb * 8) * 64);
        }
        // prefetch next tile's chunks cb, cb+1
        if (tt < 5) {
            const float* An = Ab + k0 + 64;
            va[0] = *(const float4*)(An);
            va[1] = *(const float4*)(An + 4);
            va[2] = *(const float4*)(An + 8);
            va[3] = *(const float4*)(An + 12);
        }
        __syncthreads();
#pragma unroll
        for (int kk = 0; kk < 2; ++kk) {
            s16x8 af[4], bf[6];
#pragma unroll
            for (int m = 0; m < 4; ++m) {
                const int row = wr + m * 16 + fr;
                const int x   = (kk * 4 + fx) ^ (row & 7);
                af[m] = *(const s16x8*)(sm.s.A + row * 64 + x * 8);
            }
#pragma unroll
            for (int n = 0; n < 6; ++n) {
                const int row = wc + n * 16 + fr;
                const int x   = (kk * 4 + fx) ^ (row & 7);
                bf[n] = *(const s16x8*)(sm.s.B + row * 64 + x * 8);
            }
#pragma unroll
            for (int m = 0; m < 4; ++m)
#pragma unroll
                for (int n = 0; n < 6; ++n)
                    acc[m][n] = __builtin_amdgcn_mfma_f32_16x16x32_bf16(
                        af[m], bf[n], acc[m][n], 0, 0, 0);
        }
    }

    // fused row-sum: 2 threads share row ra
    rsum += __shfl_xor(rsum, 1, 64);
    if (rs != nullptr && l0 == 0 && (t & 1) == 0)
        rs[(size_t)(i0 + ra) * N + j] = rsum;

    // epilogue: 2 phases of 64 bf16 rows in LDS [64][200]
    const int rq = fx * 4;
    __syncthreads();
#pragma unroll
    for (int p = 0; p < 2; ++p) {
        if ((wv >> 1) == p) {
#pragma unroll
            for (int m = 0; m < 4; ++m)
#pragma unroll
                for (int n = 0; n < 6; ++n)
#pragma unroll
                    for (int r = 0; r < 4; ++r)
                        sm.C[(m * 16 + rq + r) * 200 + wc + n * 16 + fr] =
                            f32_to_bf16(acc[m][n][r]);
        }
        __syncthreads();
#pragma unroll
        for (int it = 0; it < 6; ++it) {
            const int cid = it * 256 + t;
            const int row = cid / 24;
            const int c   = cid % 24;
            *(uint4*)(e + (size_t)(i0 + p * 64 + row) * N2 + (size_t)j * N + l0 + c * 8) =
                *(const uint4*)&sm.C[row * 200 + c * 8];
        }
        if (p == 0) __syncthreads();
    }
}

// ---------------------------------------------------------------------------
// k_eT: et[i][l][m] = e[i][m][l]
// ---------------------------------------------------------------------------
__global__ __launch_bounds__(256) void k_eT(const unsigned short* __restrict__ e,
                                            unsigned short* __restrict__ et) {
    __shared__ unsigned short tile[64][68];
    const int m0 = blockIdx.x * 64, l0 = blockIdx.y * 64;
    const size_t ib = (size_t)blockIdx.z * N2;
    const int t  = threadIdx.x;
    const int c4 = (t & 15) * 4, r = t >> 4;
#pragma unroll
    for (int p = 0; p < 4; ++p) {
        ushort4 v = *(const ushort4*)(e + ib + (size_t)(m0 + r + 16 * p) * N + l0 + c4);
        tile[c4 + 0][r + 16 * p] = v.x;
        tile[c4 + 1][r + 16 * p] = v.y;
        tile[c4 + 2][r + 16 * p] = v.z;
        tile[c4 + 3][r + 16 * p] = v.w;
    }
    __syncthreads();
#pragma unroll
    for (int p = 0; p < 4; ++p) {
        const int lr = r + 16 * p;
        ushort4 v = *(const ushort4*)&tile[lr][c4];
        *(ushort4*)(et + ib + (size_t)(l0 + lr) * N + m0 + c4) = v;
    }
}

// ---------------------------------------------------------------------------
// k_attn: one wave per row (i,j); rs precomputed by k_e5
// ---------------------------------------------------------------------------
template <bool HAVE_RS>
__global__ __launch_bounds__(256) void k_attn(const float* __restrict__ in,
                                              const float* __restrict__ w,
                                              const float* __restrict__ rs,
                                              unsigned short* __restrict__ attn) {
    const int row  = blockIdx.x * 4 + (threadIdx.x >> 6);
    const int lane = threadIdx.x & 63;
    const int jr   = row % N;

    const float2* wp = (const float2*)(w + (size_t)row * N);

    float2 wv[3];
    float rs_in = 0.f, rs_w = 0.f;
#pragma unroll
    for (int c = 0; c < 3; ++c) {
        wv[c] = wp[lane + 64 * c];
        rs_w += wv[c].x + wv[c].y;
    }
    if (HAVE_RS) {
#pragma unroll
        for (int s = 1; s < 64; s <<= 1) rs_w += __shfl_xor(rs_w, s, 64);
        rs_in = rs[row];
    } else {
        const float2* ip = (const float2*)(in + (size_t)row * N);
#pragma unroll
        for (int c = 0; c < 3; ++c) {
            float2 iv = ip[lane + 64 * c];
            rs_in += iv.x + iv.y;
        }
#pragma unroll
        for (int s = 1; s < 64; s <<= 1) {
            rs_in += __shfl_xor(rs_in, s, 64);
            rs_w  += __shfl_xor(rs_w, s, 64);
        }
    }
    const float scale = rs_in / (0.5f + rs_w);

    float2 q[3];
    float mx = -INFINITY;
#pragma unroll
    for (int c = 0; c < 3; ++c) {
        const int l = (lane + 64 * c) * 2;
        q[c].x = (l     <= jr) ? scale * wv[c].x : -INFINITY;
        q[c].y = (l + 1 <= jr) ? scale * wv[c].y : -INFINITY;
        mx = fmaxf(mx, fmaxf(q[c].x, q[c].y));
    }
#pragma unroll
    for (int s = 1; s < 64; s <<= 1) mx = fmaxf(mx, __shfl_xor(mx, s, 64));

    float2 p[3];
    float sum = 0.f;
#pragma unroll
    for (int c = 0; c < 3; ++c) {
        const int l = (lane + 64 * c) * 2;
        p[c].x = (l     <= jr) ? exp2f((q[c].x - mx) * 1.44269504f) : 0.f;
        p[c].y = (l + 1 <= jr) ? exp2f((q[c].y - mx) * 1.44269504f) : 0.f;
        sum += p[c].x + p[c].y;
    }
#pragma unroll
    for (int s = 1; s < 64; s <<= 1) sum += __shfl_xor(sum, s, 64);
    const float inv = 1.f / sum;
    unsigned int* ap = (unsigned int*)(attn + (size_t)row * N);
#pragma unroll
    for (int c = 0; c < 3; ++c)
        ap[lane + 64 * c] = pk2(p[c].x * inv, p[c].y * inv);
}

// ---------------------------------------------------------------------------
// k_av3: per i: out[j0..j0+63, l0..l0+127] = attn[i] @ et[i]^T, K <= j0+64
// (r11 structure, unchanged: A reg-staged, B gll dbuf, counted vmcnt)
// ---------------------------------------------------------------------------
__global__ __launch_bounds__(256, 4) void k_av3(const unsigned short* __restrict__ attn,
                                                const unsigned short* __restrict__ et,
                                                float* __restrict__ out) {
    __shared__ union {
        struct { unsigned short A[64 * 64]; unsigned short B[2][128 * 64]; } s; // 40960 B
        float C[64 * 132];
    } sm;

    const int lin = blockIdx.x;               // 6912 = 8 * 864
    const int swz = (lin & 7) * 864 + (lin >> 3);
    const int i   = swz / 18;
    const int sub = swz % 18;
    const int j0  = (sub / 3) * 64;
    const int l0  = (sub % 3) * 128;
    const int nt  = (j0 >> 6) + 1;            // K tiles: 1..6

    const int t = threadIdx.x, lane = t & 63, wv = t >> 6;
    const int fr = lane & 15, fx = lane >> 4;
    const int wr = (wv >> 1) * 32;
    const int wc = (wv & 1) * 64;
    const int rb_off = lane >> 3;
    const int p8     = lane & 7;

    const int ra = t >> 2, ca = (t & 3) * 2;
    const unsigned short* Ab = attn + (size_t)i * N2 + (size_t)(j0 + ra) * N + ca * 8;
    unsigned short* AsW0 = sm.s.A + ra * 64 + (((ca + 0) ^ (ra & 7)) * 8);
    unsigned short* AsW1 = sm.s.A + ra * 64 + (((ca + 1) ^ (ra & 7)) * 8);

    const unsigned short* Bg = et + (size_t)i * N2 + (size_t)l0 * N;

    f32x4 acc[2][4];
#pragma unroll
    for (int m = 0; m < 2; ++m)
#pragma unroll
        for (int n = 0; n < 4; ++n) acc[m][n] = (f32x4){0.f, 0.f, 0.f, 0.f};

    uint4 va0 = *(const uint4*)(Ab);
    uint4 va1 = *(const uint4*)(Ab + 8);

    {
        unsigned short* B0 = sm.s.B[0];
#pragma unroll
        for (int op = 0; op < 4; ++op) {
            const int rr = wv * 32 + op * 8 + rb_off;
            const int sc = p8 ^ (rr & 7);
            gll16(Bg + (size_t)rr * N + sc * 8, B0 + (wv * 32 + op * 8) * 64);
        }
        asm volatile("s_waitcnt vmcnt(0)" ::: "memory");
    }

    unsigned short* Bc = sm.s.B[0];
    unsigned short* Bn = sm.s.B[1];

    for (int tt = 0; tt < nt; ++tt) {
        *(uint4*)AsW0 = va0;
        *(uint4*)AsW1 = va1;
        if (tt + 1 < nt) {
            const int kn = (tt + 1) * 64;
#pragma unroll
            for (int op = 0; op < 4; ++op) {
                const int rr = wv * 32 + op * 8 + rb_off;
                const int sc = p8 ^ (rr & 7);
                gll16(Bg + (size_t)rr * N + kn + sc * 8, Bn + (wv * 32 + op * 8) * 64);
            }
            __builtin_amdgcn_sched_barrier(0);
            va0 = *(const uint4*)(Ab + kn);
            va1 = *(const uint4*)(Ab + kn + 8);
        }
        WAITL0;
        BAR;
        __builtin_amdgcn_s_setprio(1);
#pragma unroll
        for (int kk = 0; kk < 2; ++kk) {
            s16x8 af[2], bf[4];
#pragma unroll
            for (int m = 0; m < 2; ++m) {
                const int row = wr + m * 16 + fr;
                const int x   = (kk * 4 + fx) ^ (row & 7);
                af[m] = *(const s16x8*)(sm.s.A + row * 64 + x * 8);
            }
#pragma unroll
            for (int n = 0; n < 4; ++n) {
                const int row = wc + n * 16 + fr;
                const int x   = (kk * 4 + fx) ^ (row & 7);
                bf[n] = *(const s16x8*)(Bc + row * 64 + x * 8);
            }
#pragma unroll
            for (int m = 0; m < 2; ++m)
#pragma unroll
                for (int n = 0; n < 4; ++n)
                    acc[m][n] = __builtin_amdgcn_mfma_f32_16x16x32_bf16(
                        af[m], bf[n], acc[m][n], 0, 0, 0);
        }
        __builtin_amdgcn_s_setprio(0);
        if (tt + 1 < nt) {
            asm volatile("s_waitcnt vmcnt(2)" ::: "memory");
        }
        BAR;
        unsigned short* tp = Bc; Bc = Bn; Bn = tp;
    }

    __syncthreads();
    const int rq = fx * 4;
#pragma unroll
    for (int m = 0; m < 2; ++m)
#pragma unroll
        for (int n = 0; n < 4; ++n)
#pragma unroll
            for (int r = 0; r < 4; ++r)
                sm.C[(wr + m * 16 + rq + r) * 132 + wc + n * 16 + fr] = acc[m][n][r];
    __syncthreads();
#pragma unroll
    for (int it = 0; it < 8; ++it) {
        const int cid = it * 256 + t;
        const int row = cid >> 5;
        const int c   = cid & 31;
        *(float4*)(out + (size_t)i * N2 + (size_t)(j0 + row) * N + l0 + c * 4) =
            *(const float4*)&sm.C[row * 132 + c * 4];
    }
}

extern "C" void kernel_launch(void* const* d_in, const int* in_sizes, int n_in,
                              void* d_out, int out_size, void* d_ws, size_t ws_size,
                              hipStream_t stream) {
    const float* in = (const float*)d_in[0];
    const float* w  = (const float*)d_in[1];
    float* out      = (float*)d_out;

    unsigned short* r0 = (unsigned short*)d_ws;       // wt -> et
    unsigned short* r1 = (unsigned short*)d_ws + N3;  // e  -> attn
    const bool have_rs = ws_size >= 2 * N3 * sizeof(unsigned short) + (size_t)N2 * sizeof(float);
    float* rs = have_rs ? (float*)((unsigned short*)d_ws + 2 * N3) : nullptr;

    kT<<<dim3(N2 / 64, N / 64), 256, 0, stream>>>(w, r0);
    k_e5<<<dim3(2304), 256, 0, stream>>>(in, r0, r1, rs);
    k_eT<<<dim3(6, 6, N), 256, 0, stream>>>(r1, r0);
    if (have_rs)
        k_attn<true><<<dim3(N2 / 4), 256, 0, stream>>>(in, w, rs, r1);
    else
        k_attn<false><<<dim3(N2 / 4), 256, 0, stream>>>(in, w, nullptr, r1);
    k_av3<<<dim3(6912), 256, 0, stream>>>(r1, r0, out);
}

// Round 15
// 392.191 us; speedup vs baseline: 1.3478x; 1.3478x over previous
//
#include <hip/hip_runtime.h>
#include <hip/hip_bf16.h>

// Model_39676907885326: out = softmax(causal(q)) @ e
//   e[i,j,l]  = sum_k in[i,j,k] * w[l,k,j]
//   attn[i,j,l] = softmax_{l<=j}( (sum_k in[i,j,k]) * w[i,j,l] / (0.5 + sum_l w[i,j,l]) )
//   out[i]    = attn[i] @ e[i]
//
// Pipeline (ws regions):
//   R0 [0, N3) bf16        : wt[j][l][k]  ->  et[i][l][m]
//   R1 [N3, 2*N3) bf16     : e[i][j][l]   ->  attn[i][j][m]
//   RS [2*N3 ..) fp32 N2   : rs[i][j]
//   kT -> k_e3(+rs) -> k_eT -> k_attn(rs) -> k_av3
//
// R15: exact revert to the best verified state (r11, 393.66 us). r14's
// 128x192 tile spilled (180 regs > 170 budget, WRITE 114->374 MB) and its
// L2-reuse theory was refuted. Plateau analysis: GEMMs are latency-bound at
// ~130+118 us, invariant to occupancy/pipelining/tile-shape; all other
// kernels at the 6.3 TB/s BW floor.

#define N 384
#define N2 (N * N)
#define BK 64
static const size_t N3 = (size_t)N * N * N;

typedef __attribute__((ext_vector_type(8))) short s16x8;
typedef __attribute__((ext_vector_type(4))) float f32x4;

#define AS1 __attribute__((address_space(1)))
#define AS3 __attribute__((address_space(3)))
__device__ __forceinline__ void gll16(const void* g, void* l) {
    __builtin_amdgcn_global_load_lds((const AS1 unsigned int*)g,
                                     (AS3 unsigned int*)l, 16, 0, 0);
}
#define WAITL0 asm volatile("s_waitcnt lgkmcnt(0)" ::: "memory")
#define BAR    __builtin_amdgcn_s_barrier()

__device__ __forceinline__ unsigned short f32_to_bf16(float f) {
    unsigned int u = __float_as_uint(f);
    u += 0x7FFFu + ((u >> 16) & 1u);
    return (unsigned short)(u >> 16);
}
__device__ __forceinline__ unsigned int pk2(float a, float b) {
    return (unsigned int)f32_to_bf16(a) | ((unsigned int)f32_to_bf16(b) << 16);
}

// ---------------------------------------------------------------------------
// kT: wt[j*N2 + r] = bf16(w[r*N + j]), r = l*N+k
// ---------------------------------------------------------------------------
__global__ __launch_bounds__(256) void kT(const float* __restrict__ w,
                                          unsigned short* __restrict__ wt) {
    __shared__ unsigned short tile[64][68];
    const int r0 = blockIdx.x * 64;
    const int j0 = blockIdx.y * 64;
    const int tx = threadIdx.x & 63;
    const int ty = threadIdx.x >> 6;
#pragma unroll
    for (int p = 0; p < 16; ++p) {
        const int r = ty * 16 + p;
        tile[r][tx] = f32_to_bf16(w[(size_t)(r0 + r) * N + j0 + tx]);
    }
    __syncthreads();
#pragma unroll
    for (int p = 0; p < 16; ++p) {
        const int jj = ty * 16 + p;
        wt[(size_t)(j0 + jj) * N2 + r0 + tx] = tile[tx][jj];
    }
}

// ---------------------------------------------------------------------------
// k_e3: per j: e[i0..i0+63, j, l0..l0+127] = in[i,j,:] . wt[j][l][:]
// BM=64, BN=128. A reg-staged (+fused rsum); B gll double-buffered with
// counted vmcnt(4) so B(t+1) latency hides under MFMA(t).
// ---------------------------------------------------------------------------
__global__ __launch_bounds__(256, 4) void k_e3(const float* __restrict__ in,
                                               const unsigned short* __restrict__ wt,
                                               unsigned short* __restrict__ e,
                                               float* __restrict__ rs) {
    __shared__ union {
        struct { unsigned short A[64 * 64]; unsigned short B[2][128 * 64]; } s; // 40960 B
        unsigned short C[64 * 136];
    } sm;

    const int lin = blockIdx.x;               // 6912 = 8 * 864
    const int swz = (lin & 7) * 864 + (lin >> 3);
    const int j   = swz / 18;
    const int sub = swz % 18;
    const int i0  = (sub / 3) * 64;
    const int l0  = (sub % 3) * 128;

    const int t = threadIdx.x, lane = t & 63, wv = t >> 6;
    const int fr = lane & 15, fx = lane >> 4;
    const int wr = (wv >> 1) * 32;            // output row offset of wave
    const int wc = (wv & 1) * 64;             // output col offset of wave
    const int rb_off = lane >> 3;
    const int p8     = lane & 7;

    // A path (reg-staged): thread -> row ra, chunks ca, ca+1
    const int ra = t >> 2, ca = (t & 3) * 2;
    const float* Ab = in + (size_t)(i0 + ra) * N2 + (size_t)j * N + ca * 8;
    unsigned short* AsW0 = sm.s.A + ra * 64 + (((ca + 0) ^ (ra & 7)) * 8);
    unsigned short* AsW1 = sm.s.A + ra * 64 + (((ca + 1) ^ (ra & 7)) * 8);

    const unsigned short* Wj = wt + (size_t)j * N2 + (size_t)l0 * N;

    f32x4 acc[2][4];
#pragma unroll
    for (int m = 0; m < 2; ++m)
#pragma unroll
        for (int n = 0; n < 4; ++n) acc[m][n] = (f32x4){0.f, 0.f, 0.f, 0.f};

    float rsum = 0.f;

    float4 va[4];
    va[0] = *(const float4*)(Ab);
    va[1] = *(const float4*)(Ab + 4);
    va[2] = *(const float4*)(Ab + 8);
    va[3] = *(const float4*)(Ab + 12);

    // prologue: B(0) -> buf0, drain
    {
        unsigned short* B0 = sm.s.B[0];
#pragma unroll
        for (int op = 0; op < 4; ++op) {
            const int rr = wv * 32 + op * 8 + rb_off;
            const int sc = p8 ^ (rr & 7);
            gll16(Wj + (size_t)rr * N + sc * 8, B0 + (wv * 32 + op * 8) * 64);
        }
        asm volatile("s_waitcnt vmcnt(0)" ::: "memory");
    }

    unsigned short* Bc = sm.s.B[0];
    unsigned short* Bn = sm.s.B[1];

#pragma unroll
    for (int tt = 0; tt < 6; ++tt) {
        // stage A(tt) from regs (+rsum)
        rsum += (va[0].x + va[0].y + va[0].z + va[0].w) +
                (va[1].x + va[1].y + va[1].z + va[1].w) +
                (va[2].x + va[2].y + va[2].z + va[2].w) +
                (va[3].x + va[3].y + va[3].z + va[3].w);
        {
            uint4 a0, a1;
            a0.x = pk2(va[0].x, va[0].y); a0.y = pk2(va[0].z, va[0].w);
            a0.z = pk2(va[1].x, va[1].y); a0.w = pk2(va[1].z, va[1].w);
            a1.x = pk2(va[2].x, va[2].y); a1.y = pk2(va[2].z, va[2].w);
            a1.z = pk2(va[3].x, va[3].y); a1.w = pk2(va[3].z, va[3].w);
            *(uint4*)AsW0 = a0;
            *(uint4*)AsW1 = a1;
        }
        if (tt < 5) {
            const int kn = (tt + 1) * 64;
            // issue B(tt+1) glls FIRST (order pinned for the counted vmcnt)
#pragma unroll
            for (int op = 0; op < 4; ++op) {
                const int rr = wv * 32 + op * 8 + rb_off;
                const int sc = p8 ^ (rr & 7);
                gll16(Wj + (size_t)rr * N + kn + sc * 8, Bn + (wv * 32 + op * 8) * 64);
            }
            __builtin_amdgcn_sched_barrier(0);
            const float* An = Ab + kn;
            va[0] = *(const float4*)(An);
            va[1] = *(const float4*)(An + 4);
            va[2] = *(const float4*)(An + 8);
            va[3] = *(const float4*)(An + 12);
        }
        WAITL0;
        BAR;
        __builtin_amdgcn_s_setprio(1);
#pragma unroll
        for (int kk = 0; kk < 2; ++kk) {
            s16x8 af[2], bf[4];
#pragma unroll
            for (int m = 0; m < 2; ++m) {
                const int row = wr + m * 16 + fr;
                const int x   = (kk * 4 + fx) ^ (row & 7);
                af[m] = *(const s16x8*)(sm.s.A + row * 64 + x * 8);
            }
#pragma unroll
            for (int n = 0; n < 4; ++n) {
                const int row = wc + n * 16 + fr;
                const int x   = (kk * 4 + fx) ^ (row & 7);
                bf[n] = *(const s16x8*)(Bc + row * 64 + x * 8);
            }
#pragma unroll
            for (int m = 0; m < 2; ++m)
#pragma unroll
                for (int n = 0; n < 4; ++n)
                    acc[m][n] = __builtin_amdgcn_mfma_f32_16x16x32_bf16(
                        af[m], bf[n], acc[m][n], 0, 0, 0);
        }
        __builtin_amdgcn_s_setprio(0);
        if (tt < 5) {
            // retire the 4 B-glls; leave the 4 A-loads in flight
            asm volatile("s_waitcnt vmcnt(4)" ::: "memory");
        }
        BAR;   // release As + publish B(tt+1)
        unsigned short* tp = Bc; Bc = Bn; Bn = tp;
    }

    rsum += __shfl_xor(rsum, 1, 64);
    rsum += __shfl_xor(rsum, 2, 64);
    if (rs != nullptr && l0 == 0 && (t & 3) == 0)
        rs[(size_t)(i0 + ra) * N + j] = rsum;

    // epilogue: 64x128 bf16 tile in LDS, stream full lines
    __syncthreads();
    const int rq = fx * 4;
#pragma unroll
    for (int m = 0; m < 2; ++m)
#pragma unroll
        for (int n = 0; n < 4; ++n)
#pragma unroll
            for (int r = 0; r < 4; ++r)
                sm.C[(wr + m * 16 + rq + r) * 136 + wc + n * 16 + fr] =
                    f32_to_bf16(acc[m][n][r]);
    __syncthreads();
#pragma unroll
    for (int it = 0; it < 4; ++it) {
        const int cid = it * 256 + t;
        const int row = cid >> 4;
        const int c   = cid & 15;
        *(uint4*)(e + (size_t)(i0 + row) * N2 + (size_t)j * N + l0 + c * 8) =
            *(const uint4*)&sm.C[row * 136 + c * 8];
    }
}

// ---------------------------------------------------------------------------
// k_eT: et[i][l][m] = e[i][m][l]
// ---------------------------------------------------------------------------
__global__ __launch_bounds__(256) void k_eT(const unsigned short* __restrict__ e,
                                            unsigned short* __restrict__ et) {
    __shared__ unsigned short tile[64][68];
    const int m0 = blockIdx.x * 64, l0 = blockIdx.y * 64;
    const size_t ib = (size_t)blockIdx.z * N2;
    const int t  = threadIdx.x;
    const int c4 = (t & 15) * 4, r = t >> 4;
#pragma unroll
    for (int p = 0; p < 4; ++p) {
        ushort4 v = *(const ushort4*)(e + ib + (size_t)(m0 + r + 16 * p) * N + l0 + c4);
        tile[c4 + 0][r + 16 * p] = v.x;
        tile[c4 + 1][r + 16 * p] = v.y;
        tile[c4 + 2][r + 16 * p] = v.z;
        tile[c4 + 3][r + 16 * p] = v.w;
    }
    __syncthreads();
#pragma unroll
    for (int p = 0; p < 4; ++p) {
        const int lr = r + 16 * p;
        ushort4 v = *(const ushort4*)&tile[lr][c4];
        *(ushort4*)(et + ib + (size_t)(l0 + lr) * N + m0 + c4) = v;
    }
}

// ---------------------------------------------------------------------------
// k_attn: one wave per row (i,j); rs precomputed by k_e3
// ---------------------------------------------------------------------------
template <bool HAVE_RS>
__global__ __launch_bounds__(256) void k_attn(const float* __restrict__ in,
                                              const float* __restrict__ w,
                                              const float* __restrict__ rs,
                                              unsigned short* __restrict__ attn) {
    const int row  = blockIdx.x * 4 + (threadIdx.x >> 6);
    const int lane = threadIdx.x & 63;
    const int jr   = row % N;

    const float2* wp = (const float2*)(w + (size_t)row * N);

    float2 wv[3];
    float rs_in = 0.f, rs_w = 0.f;
#pragma unroll
    for (int c = 0; c < 3; ++c) {
        wv[c] = wp[lane + 64 * c];
        rs_w += wv[c].x + wv[c].y;
    }
    if (HAVE_RS) {
#pragma unroll
        for (int s = 1; s < 64; s <<= 1) rs_w += __shfl_xor(rs_w, s, 64);
        rs_in = rs[row];
    } else {
        const float2* ip = (const float2*)(in + (size_t)row * N);
#pragma unroll
        for (int c = 0; c < 3; ++c) {
            float2 iv = ip[lane + 64 * c];
            rs_in += iv.x + iv.y;
        }
#pragma unroll
        for (int s = 1; s < 64; s <<= 1) {
            rs_in += __shfl_xor(rs_in, s, 64);
            rs_w  += __shfl_xor(rs_w, s, 64);
        }
    }
    const float scale = rs_in / (0.5f + rs_w);

    float2 q[3];
    float mx = -INFINITY;
#pragma unroll
    for (int c = 0; c < 3; ++c) {
        const int l = (lane + 64 * c) * 2;
        q[c].x = (l     <= jr) ? scale * wv[c].x : -INFINITY;
        q[c].y = (l + 1 <= jr) ? scale * wv[c].y : -INFINITY;
        mx = fmaxf(mx, fmaxf(q[c].x, q[c].y));
    }
#pragma unroll
    for (int s = 1; s < 64; s <<= 1) mx = fmaxf(mx, __shfl_xor(mx, s, 64));

    float2 p[3];
    float sum = 0.f;
#pragma unroll
    for (int c = 0; c < 3; ++c) {
        const int l = (lane + 64 * c) * 2;
        p[c].x = (l     <= jr) ? exp2f((q[c].x - mx) * 1.44269504f) : 0.f;
        p[c].y = (l + 1 <= jr) ? exp2f((q[c].y - mx) * 1.44269504f) : 0.f;
        sum += p[c].x + p[c].y;
    }
#pragma unroll
    for (int s = 1; s < 64; s <<= 1) sum += __shfl_xor(sum, s, 64);
    const float inv = 1.f / sum;
    unsigned int* ap = (unsigned int*)(attn + (size_t)row * N);
#pragma unroll
    for (int c = 0; c < 3; ++c)
        ap[lane + 64 * c] = pk2(p[c].x * inv, p[c].y * inv);
}

// ---------------------------------------------------------------------------
// k_av3: per i: out[j0..j0+63, l0..l0+127] = attn[i] @ et[i]^T, K <= j0+64
// Same pipeline: A (attn, bf16) reg-staged; B (et) gll dbuf, vmcnt(2).
// ---------------------------------------------------------------------------
__global__ __launch_bounds__(256, 4) void k_av3(const unsigned short* __restrict__ attn,
                                                const unsigned short* __restrict__ et,
                                                float* __restrict__ out) {
    __shared__ union {
        struct { unsigned short A[64 * 64]; unsigned short B[2][128 * 64]; } s; // 40960 B
        float C[64 * 132];   // 33792 B
    } sm;

    const int lin = blockIdx.x;               // 6912 = 8 * 864
    const int swz = (lin & 7) * 864 + (lin >> 3);
    const int i   = swz / 18;
    const int sub = swz % 18;
    const int j0  = (sub / 3) * 64;
    const int l0  = (sub % 3) * 128;
    const int nt  = (j0 >> 6) + 1;            // K tiles: 1..6

    const int t = threadIdx.x, lane = t & 63, wv = t >> 6;
    const int fr = lane & 15, fx = lane >> 4;
    const int wr = (wv >> 1) * 32;
    const int wc = (wv & 1) * 64;
    const int rb_off = lane >> 3;
    const int p8     = lane & 7;

    // A path (reg-staged bf16): row ra, chunks ca, ca+1
    const int ra = t >> 2, ca = (t & 3) * 2;
    const unsigned short* Ab = attn + (size_t)i * N2 + (size_t)(j0 + ra) * N + ca * 8;
    unsigned short* AsW0 = sm.s.A + ra * 64 + (((ca + 0) ^ (ra & 7)) * 8);
    unsigned short* AsW1 = sm.s.A + ra * 64 + (((ca + 1) ^ (ra & 7)) * 8);

    const unsigned short* Bg = et + (size_t)i * N2 + (size_t)l0 * N;

    f32x4 acc[2][4];
#pragma unroll
    for (int m = 0; m < 2; ++m)
#pragma unroll
        for (int n = 0; n < 4; ++n) acc[m][n] = (f32x4){0.f, 0.f, 0.f, 0.f};

    uint4 va0 = *(const uint4*)(Ab);
    uint4 va1 = *(const uint4*)(Ab + 8);

    // prologue: B(0) -> buf0, drain
    {
        unsigned short* B0 = sm.s.B[0];
#pragma unroll
        for (int op = 0; op < 4; ++op) {
            const int rr = wv * 32 + op * 8 + rb_off;
            const int sc = p8 ^ (rr & 7);
            gll16(Bg + (size_t)rr * N + sc * 8, B0 + (wv * 32 + op * 8) * 64);
        }
        asm volatile("s_waitcnt vmcnt(0)" ::: "memory");
    }

    unsigned short* Bc = sm.s.B[0];
    unsigned short* Bn = sm.s.B[1];

    for (int tt = 0; tt < nt; ++tt) {
        *(uint4*)AsW0 = va0;
        *(uint4*)AsW1 = va1;
        if (tt + 1 < nt) {
            const int kn = (tt + 1) * 64;
#pragma unroll
            for (int op = 0; op < 4; ++op) {
                const int rr = wv * 32 + op * 8 + rb_off;
                const int sc = p8 ^ (rr & 7);
                gll16(Bg + (size_t)rr * N + kn + sc * 8, Bn + (wv * 32 + op * 8) * 64);
            }
            __builtin_amdgcn_sched_barrier(0);
            va0 = *(const uint4*)(Ab + kn);
            va1 = *(const uint4*)(Ab + kn + 8);
        }
        WAITL0;
        BAR;
        __builtin_amdgcn_s_setprio(1);
#pragma unroll
        for (int kk = 0; kk < 2; ++kk) {
            s16x8 af[2], bf[4];
#pragma unroll
            for (int m = 0; m < 2; ++m) {
                const int row = wr + m * 16 + fr;
                const int x   = (kk * 4 + fx) ^ (row & 7);
                af[m] = *(const s16x8*)(sm.s.A + row * 64 + x * 8);
            }
#pragma unroll
            for (int n = 0; n < 4; ++n) {
                const int row = wc + n * 16 + fr;
                const int x   = (kk * 4 + fx) ^ (row & 7);
                bf[n] = *(const s16x8*)(Bc + row * 64 + x * 8);
            }
#pragma unroll
            for (int m = 0; m < 2; ++m)
#pragma unroll
                for (int n = 0; n < 4; ++n)
                    acc[m][n] = __builtin_amdgcn_mfma_f32_16x16x32_bf16(
                        af[m], bf[n], acc[m][n], 0, 0, 0);
        }
        __builtin_amdgcn_s_setprio(0);
        if (tt + 1 < nt) {
            // retire the 4 B-glls; leave the 2 A-loads in flight
            asm volatile("s_waitcnt vmcnt(2)" ::: "memory");
        }
        BAR;
        unsigned short* tp = Bc; Bc = Bn; Bn = tp;
    }

    // epilogue: 64x128 fp32 tile in LDS, stream float4
    __syncthreads();
    const int rq = fx * 4;
#pragma unroll
    for (int m = 0; m < 2; ++m)
#pragma unroll
        for (int n = 0; n < 4; ++n)
#pragma unroll
            for (int r = 0; r < 4; ++r)
                sm.C[(wr + m * 16 + rq + r) * 132 + wc + n * 16 + fr] = acc[m][n][r];
    __syncthreads();
#pragma unroll
    for (int it = 0; it < 8; ++it) {
        const int cid = it * 256 + t;
        const int row = cid >> 5;
        const int c   = cid & 31;
        *(float4*)(out + (size_t)i * N2 + (size_t)(j0 + row) * N + l0 + c * 4) =
            *(const float4*)&sm.C[row * 132 + c * 4];
    }
}

extern "C" void kernel_launch(void* const* d_in, const int* in_sizes, int n_in,
                              void* d_out, int out_size, void* d_ws, size_t ws_size,
                              hipStream_t stream) {
    const float* in = (const float*)d_in[0];
    const float* w  = (const float*)d_in[1];
    float* out      = (float*)d_out;

    unsigned short* r0 = (unsigned short*)d_ws;       // wt -> et
    unsigned short* r1 = (unsigned short*)d_ws + N3;  // e  -> attn
    const bool have_rs = ws_size >= 2 * N3 * sizeof(unsigned short) + (size_t)N2 * sizeof(float);
    float* rs = have_rs ? (float*)((unsigned short*)d_ws + 2 * N3) : nullptr;

    kT<<<dim3(N2 / 64, N / 64), 256, 0, stream>>>(w, r0);
    k_e3<<<dim3(6912), 256, 0, stream>>>(in, r0, r1, rs);
    k_eT<<<dim3(6, 6, N), 256, 0, stream>>>(r1, r0);
    if (have_rs)
        k_attn<true><<<dim3(N2 / 4), 256, 0, stream>>>(in, w, rs, r1);
    else
        k_attn<false><<<dim3(N2 / 4), 256, 0, stream>>>(in, w, nullptr, r1);
    k_av3<<<dim3(6912), 256, 0, stream>>>(r1, r0, out);
}